// Round 11
// baseline (357.251 us; speedup 1.0000x reference)
//
#include <hip/hip_runtime.h>
#include <type_traits>

typedef __attribute__((ext_vector_type(8))) short short8;
typedef __attribute__((ext_vector_type(4))) short short4v;
typedef __attribute__((ext_vector_type(4))) float f32x4;
typedef unsigned short u16;
typedef unsigned int u32;

#define N_EDGES 448

// ws layout (u16 units); all-bf16 packs
#define WS_ADJA 0                    // 4096: A_norm, MFMA A-operand pack
#define WS_ADJB 4096                 // 4096: A_norm^T, MFMA B-operand pack
#define WS_W1   8192                 // 256x512
#define WS_W2   139264               // 512x512
#define WS_W3   401408               // 512x256
#define WS_DUM  532480               // dummy 256 | b1 512 | b2 512 | b3 256
#define WS_B1   (WS_DUM + 256)
#define WS_B2   (WS_DUM + 768)
#define WS_B3   (WS_DUM + 1280)
#define WS_QE   534528               // 1024x256 qembs as bf16, row-major
#define WS_FLAG 796672               // u32: 1 = f32 inputs, 0 = bf16

__device__ __forceinline__ float bf2f(u16 v) {
    u32 u = ((u32)v) << 16;
    return __builtin_bit_cast(float, u);
}
__device__ __forceinline__ u16 f2bf(float f) {          // RNE (prep)
    u32 u = __builtin_bit_cast(u32, f);
    u32 r = u + 0x7FFFu + ((u >> 16) & 1u);
    return (u16)(r >> 16);
}
__device__ __forceinline__ u16 f2bf_fast(float f) {     // round-half-up (hot)
    u32 u = __builtin_bit_cast(u32, f);
    return (u16)((u + 0x8000u) >> 16);
}
__device__ __forceinline__ float ldf(const void* p, int idx, u32 isf32) {
    return isf32 ? ((const float*)p)[idx] : bf2f(((const u16*)p)[idx]);
}

// ---------------------------------------------------------------------------
// prep: 512 blocks x 512 threads (proven ~10 us).
//   all blocks: 2 weight chunks (t<128) + qembs->bf16 copy (t>=256)
//   block 0: adjacency + flag;  block 1: biases/dummy
// ---------------------------------------------------------------------------
__global__ __launch_bounds__(512) void prep(
    const int* __restrict__ eidx, const void* __restrict__ ew,
    const void* __restrict__ qembs, const void* __restrict__ dummy,
    const void* __restrict__ W1, const void* __restrict__ b1,
    const void* __restrict__ W2, const void* __restrict__ b2,
    const void* __restrict__ W3, const void* __restrict__ b3,
    u16* __restrict__ ws) {
    const int t = threadIdx.x, bb = blockIdx.x;
    __shared__ u32 s_isf;
    if (t < 64) {
        const u16* qs = (const u16*)qembs;
        int c = 0;
#pragma unroll
        for (int j = 0; j < 4; j++) {
            u16 v = qs[(t * 4 + j) * 2];
            u32 e = (v >> 7) & 0xFF;
            c += (e >= 100 && e <= 134) ? 1 : 0;
        }
#pragma unroll
        for (int off = 32; off > 0; off >>= 1) c += __shfl_down(c, off, 64);
        if (t == 0) s_isf = (c < 128) ? 1u : 0u;
    }
    __syncthreads();
    const u32 isf32 = s_isf;

    if (t < 128) {
        const int bw = bb * 2 + (t >> 6);
        const int tl = t & 63;
        const void* src;
        int N, K32, dst, nt, kk;
        if (bw < 256)      { src = W1; N = 512; K32 = 8;  dst = WS_W1; nt = bw / 8;          kk = bw % 8; }
        else if (bw < 768) { src = W2; N = 512; K32 = 16; dst = WS_W2; nt = (bw - 256) / 16; kk = (bw - 256) % 16; }
        else               { src = W3; N = 256; K32 = 16; dst = WS_W3; nt = (bw - 768) / 16; kk = (bw - 768) % 16; }
        const int col = nt * 16 + (tl & 15);
        const int krow = kk * 32 + (tl >> 4) * 8;
        u16 v[8];
#pragma unroll
        for (int j = 0; j < 8; j++) v[j] = f2bf(ldf(src, (krow + j) * N + col, isf32));
        u16* o = ws + dst + (nt * K32 + kk) * 512 + tl * 8;
#pragma unroll
        for (int j = 0; j < 8; j++) o[j] = v[j];
    }
    if (t >= 256) {
        const int base = bb * 512 + (t - 256) * 2;
        ws[WS_QE + base]     = f2bf(ldf(qembs, base, isf32));
        ws[WS_QE + base + 1] = f2bf(ldf(qembs, base + 1, isf32));
    }
    if (bb == 1) {
#pragma unroll
        for (int j = 0; j < 4; j++) {
            int i = t + j * 512;
            if (i < 1792) {
                float v;
                if (i < 256)       v = ldf(dummy, i, isf32);
                else if (i < 768)  v = ldf(b1, i - 256, isf32);
                else if (i < 1280) v = ldf(b2, i - 768, isf32);
                else               v = ldf(b3, i - 1280, isf32);
                ws[WS_DUM + i] = f2bf(v);
            }
        }
    }
    if (bb == 0) {
        __shared__ float A[4096];
        __shared__ float deg[64];
        __shared__ float dinv[64];
        __shared__ int er[N_EDGES];
        __shared__ int ec[N_EDGES];
        __shared__ float ewf[N_EDGES];
        if (t < N_EDGES) {
            er[t] = eidx[t];
            ec[t] = eidx[N_EDGES + t];
            ewf[t] = ldf(ew, t, isf32);
        }
        if (t < 64) deg[t] = 1.0f;
        for (int i = t; i < 4096; i += 512) A[i] = 0.f;
        __syncthreads();
        if (t < N_EDGES) atomicAdd(&deg[ec[t]], ewf[t]);
        __syncthreads();
        if (t < 64) dinv[t] = 1.0f / sqrtf(deg[t]);
        __syncthreads();
        if (t < N_EDGES) atomicAdd(&A[ec[t] * 64 + er[t]], dinv[er[t]] * ewf[t] * dinv[ec[t]]);
        __syncthreads();
        if (t < 64) A[t * 64 + t] += dinv[t] * dinv[t];
        __syncthreads();
        for (int i = t; i < 4096; i += 512) {
            int chunk = i >> 9, m = (i >> 3) & 63, j = i & 7;
            ws[WS_ADJA + i] = f2bf(A[m * 64 + chunk * 8 + j]);
        }
        for (int i = t; i < 4096; i += 512) {
            int chunk = i >> 9, l = (i >> 3) & 63, j = i & 7;
            int ntc = chunk >> 1, kk = chunk & 1;
            int k = kk * 32 + (l >> 4) * 8 + j;
            int c2 = ntc * 16 + (l & 15);
            ws[WS_ADJB + i] = f2bf(A[c2 * 64 + k]);
        }
        if (t == 0) *(u32*)(ws + WS_FLAG) = isf32;
    }
}

// ---------------------------------------------------------------------------
// fused: pooling + 3 GCN layers. 256 blocks x 1024 threads, 2 batch elems
// per block (weights/adjB fetched once per block instead of twice per CU).
// Ping-pong BUF0/BUF1 (128 KB, 1 block/CU), one barrier per layer (R10).
// ---------------------------------------------------------------------------
__global__ __launch_bounds__(1024, 4) void fused(
    const int* __restrict__ allocs, const u16* __restrict__ ws,
    void* __restrict__ out) {

    __shared__ __align__(16) u16 BUF0[64 * 512];   // 64 KB
    __shared__ __align__(16) u16 BUF1[64 * 512];   // 64 KB

    const int t = threadIdx.x, bb = blockIdx.x;
    const int wave = t >> 6, lane = t & 63, quad = lane >> 4, nl = lane & 15;
    const u32 isf32 = *(const u32*)(ws + WS_FLAG);

    // hoisted across both elems: dummy-emb maxima seeds + A_norm^T B-frags
    float dums[4];
#pragma unroll
    for (int jj = 0; jj < 4; jj++) dums[jj] = bf2f(ws[WS_DUM + lane * 4 + jj]);
    short8 adjB[4][2];
#pragma unroll
    for (int ntc = 0; ntc < 4; ntc++)
#pragma unroll
        for (int h = 0; h < 2; h++)
            adjB[ntc][h] = *(const short8*)(ws + WS_ADJB + (ntc * 2 + h) * 512 + lane * 8);

    // layerT: mm1 (2 stripes/wave) + transpose + agg + relu/bias -> OUT A-pack.
    // scr = wave's own stripe-1 output chunks (4w+2..3), consumed before the
    // s=1 epilogue overwrites them. One barrier at end (validated R9/R10).
    auto layerT = [&](auto K32c, const u16* __restrict__ W, const u16* __restrict__ bias,
                      const u16* __restrict__ IN, u16* __restrict__ OUT) {
        constexpr int K32 = decltype(K32c)::value;
        const int s0 = wave * 2;
        u16* scr = OUT + (wave * 4 + 2) * 512;
        f32x4 acc[2][4];
#pragma unroll
        for (int s = 0; s < 2; s++)
#pragma unroll
            for (int rt = 0; rt < 4; rt++) acc[s][rt] = f32x4{0.f, 0.f, 0.f, 0.f};
#pragma unroll
        for (int kk = 0; kk < K32; kk++) {
            short8 a[4], bch[2];
#pragma unroll
            for (int rt = 0; rt < 4; rt++)
                a[rt] = *(const short8*)(IN + (kk * 4 + quad) * 512 + (rt * 16 + nl) * 8);
#pragma unroll
            for (int s = 0; s < 2; s++)
                bch[s] = *(const short8*)(W + ((s0 + s) * K32 + kk) * 512 + lane * 8);
#pragma unroll
            for (int s = 0; s < 2; s++)
#pragma unroll
                for (int rt = 0; rt < 4; rt++)
                    acc[s][rt] = __builtin_amdgcn_mfma_f32_16x16x32_bf16(a[rt], bch[s], acc[s][rt], 0, 0, 0);
        }
#pragma unroll
        for (int s = 0; s < 2; s++) {
            const int nt = s0 + s;
            f32x4 agg[4];
#pragma unroll
            for (int ntc = 0; ntc < 4; ntc++) agg[ntc] = f32x4{0.f, 0.f, 0.f, 0.f};
#pragma unroll
            for (int h = 0; h < 2; h++) {
#pragma unroll
                for (int r2 = 0; r2 < 2; r2++) {
                    f32x4 v = acc[s][2 * h + r2];
                    short4v p;
#pragma unroll
                    for (int rr = 0; rr < 4; rr++) p[rr] = (short)f2bf_fast(v[rr]);
                    *(short4v*)(scr + nl * 40 + r2 * 16 + quad * 4) = p;
                }
                short8 hwf = *(const short8*)(scr + nl * 40 + quad * 8);
#pragma unroll
                for (int ntc = 0; ntc < 4; ntc++)
                    agg[ntc] = __builtin_amdgcn_mfma_f32_16x16x32_bf16(hwf, adjB[ntc][h], agg[ntc], 0, 0, 0);
            }
            float bv[4];
#pragma unroll
            for (int rr = 0; rr < 4; rr++) bv[rr] = bf2f(bias[nt * 16 + quad * 4 + rr]);
#pragma unroll
            for (int ntc = 0; ntc < 4; ntc++) {
                short4v p;
#pragma unroll
                for (int rr = 0; rr < 4; rr++)
                    p[rr] = (short)f2bf_fast(fmaxf(agg[ntc][rr] + bv[rr], 0.f));
                *(short4v*)(OUT + (nt * 2 + (quad >> 1)) * 512 + (ntc * 16 + nl) * 8 + (quad & 1) * 4) = p;
            }
        }
        __syncthreads();
    };

    // layer3: hw3 = h2 @ W3 (1 stripe/wave); B-pack -> OUT chunks 0..31.
    auto layer3 = [&](const u16* __restrict__ W, const u16* __restrict__ IN,
                      u16* __restrict__ OUT) {
        const int nt = wave;
        u16* scr = OUT + 16384 + wave * 640;   // chunks 32+ (dead region)
        f32x4 acc[4];
#pragma unroll
        for (int rt = 0; rt < 4; rt++) acc[rt] = f32x4{0.f, 0.f, 0.f, 0.f};
#pragma unroll
        for (int kk = 0; kk < 16; kk++) {
            short8 a[4];
#pragma unroll
            for (int rt = 0; rt < 4; rt++)
                a[rt] = *(const short8*)(IN + (kk * 4 + quad) * 512 + (rt * 16 + nl) * 8);
            short8 bch = *(const short8*)(W + (nt * 16 + kk) * 512 + lane * 8);
#pragma unroll
            for (int rt = 0; rt < 4; rt++)
                acc[rt] = __builtin_amdgcn_mfma_f32_16x16x32_bf16(a[rt], bch, acc[rt], 0, 0, 0);
        }
#pragma unroll
        for (int h = 0; h < 2; h++) {
#pragma unroll
            for (int r2 = 0; r2 < 2; r2++) {
                f32x4 v = acc[2 * h + r2];
                short4v p;
#pragma unroll
                for (int rr = 0; rr < 4; rr++) p[rr] = (short)f2bf_fast(v[rr]);
                *(short4v*)(scr + nl * 40 + r2 * 16 + quad * 4) = p;
            }
            short8 hwf = *(const short8*)(scr + nl * 40 + quad * 8);
            *(short8*)(OUT + (nt * 2 + h) * 512 + lane * 8) = hwf;
        }
        __syncthreads();
    };

    for (int e = 0; e < 2; e++) {
        const int elem = bb * 2 + e;

        // ---- pooling: counting sort (aux in BUF1) + wave gather -> X in BUF0 ----
        {
            int* LIST = (int*)BUF1;
            int* CNT  = LIST + 1024;
            int* SST  = CNT + 64;
            int* WOF  = SST + 64;
            if (t < 64) CNT[t] = 0;
            __syncthreads();
            const int myc = allocs[elem * 1024 + t];
            atomicAdd(&CNT[myc], 1);
            __syncthreads();
            if (t < 64) {
                int v = CNT[t], s = v;
#pragma unroll
                for (int off = 1; off < 64; off <<= 1) {
                    int u = __shfl_up(s, off, 64);
                    if (t >= off) s += u;
                }
                SST[t] = s - v;
                WOF[t] = s - v;
            }
            __syncthreads();
            {
                int pos = atomicAdd(&WOF[myc], 1);
                LIST[pos] = t;
            }
            __syncthreads();
            const u16* wsq = ws + WS_QE;
            for (int i = 0; i < 4; i++) {
                const int c = wave * 4 + i;
                const int L = CNT[c], S = SST[c];
                float vm0 = dums[0], vm1 = dums[1], vm2 = dums[2], vm3 = dums[3];
                for (int j = 0; j < L; j++) {
                    int q = LIST[S + j];
                    uint2 r = *(const uint2*)(wsq + q * 256 + lane * 4);
                    vm0 = fmaxf(vm0, bf2f((u16)(r.x & 0xffff)));
                    vm1 = fmaxf(vm1, bf2f((u16)(r.x >> 16)));
                    vm2 = fmaxf(vm2, bf2f((u16)(r.y & 0xffff)));
                    vm3 = fmaxf(vm3, bf2f((u16)(r.y >> 16)));
                }
                short4v p;
                p[0] = (short)f2bf_fast(vm0);
                p[1] = (short)f2bf_fast(vm1);
                p[2] = (short)f2bf_fast(vm2);
                p[3] = (short)f2bf_fast(vm3);
                *(short4v*)(BUF0 + (lane >> 1) * 512 + c * 8 + (lane & 1) * 4) = p;
            }
        }
        __syncthreads();

        layerT(std::integral_constant<int, 8>{},  ws + WS_W1, ws + WS_B1, BUF0, BUF1);
        layerT(std::integral_constant<int, 16>{}, ws + WS_W2, ws + WS_B2, BUF1, BUF0);
        layer3(ws + WS_W3, BUF0, BUF1);

        // final: out = relu(A_norm @ hw3 + b3); stage f32 in BUF0, coalesced store
        {
            const int rt2 = wave & 3, nt0 = (wave >> 2) * 4;
            short8 aA[2];
#pragma unroll
            for (int h = 0; h < 2; h++)
                aA[h] = *(const short8*)(ws + WS_ADJA + (h * 4 + quad) * 512 + (rt2 * 16 + nl) * 8);
            f32x4 accv[4];
#pragma unroll
            for (int ni = 0; ni < 4; ni++) {
                const int nt = nt0 + ni;
                short8 b0v = *(const short8*)(BUF1 + (nt * 2 + 0) * 512 + lane * 8);
                short8 b1v = *(const short8*)(BUF1 + (nt * 2 + 1) * 512 + lane * 8);
                f32x4 a = f32x4{0.f, 0.f, 0.f, 0.f};
                a = __builtin_amdgcn_mfma_f32_16x16x32_bf16(aA[0], b0v, a, 0, 0, 0);
                a = __builtin_amdgcn_mfma_f32_16x16x32_bf16(aA[1], b1v, a, 0, 0, 0);
                accv[ni] = a;
            }
            float* Hf = (float*)BUF0;   // BUF0 dead after layer3's end barrier
#pragma unroll
            for (int ni = 0; ni < 4; ni++) {
                const int n = (nt0 + ni) * 16 + nl;
                const float bv = bf2f(ws[WS_B3 + n]);
#pragma unroll
                for (int rr = 0; rr < 4; rr++) {
                    const int m2 = rt2 * 16 + quad * 4 + rr;
                    Hf[m2 * 256 + n] = fmaxf(accv[ni][rr] + bv, 0.f);
                }
            }
            __syncthreads();
            if (isf32) {
                float4* outv = (float4*)((float*)out + (size_t)elem * 16384);
                const float4* Hv = (const float4*)Hf;
#pragma unroll
                for (int p4 = 0; p4 < 4; p4++) outv[p4 * 1024 + t] = Hv[p4 * 1024 + t];
            } else {
                u16* outu = (u16*)out + (size_t)elem * 16384;
#pragma unroll
                for (int p4 = 0; p4 < 4; p4++) {
                    const int idx = (p4 * 1024 + t) * 4;
                    float4 v = *(const float4*)(Hf + idx);
                    short4v pk;
                    pk[0] = (short)f2bf_fast(v.x); pk[1] = (short)f2bf_fast(v.y);
                    pk[2] = (short)f2bf_fast(v.z); pk[3] = (short)f2bf_fast(v.w);
                    *(short4v*)(outu + idx) = pk;
                }
            }
        }
        __syncthreads();   // BUF0/BUF1 free for next elem (final reads BUF1 done)
    }
}

// ---------------------------------------------------------------------------
extern "C" void kernel_launch(void* const* d_in, const int* in_sizes, int n_in,
                              void* d_out, int out_size, void* d_ws, size_t ws_size,
                              hipStream_t stream) {
    const int* allocs = (const int*)d_in[0];
    const void* qembs = d_in[1];
    const void* dummy = d_in[2];
    const int* eidx   = (const int*)d_in[3];
    const void* ew    = d_in[4];
    const void* W1 = d_in[5];
    const void* b1 = d_in[6];
    const void* W2 = d_in[7];
    const void* b2 = d_in[8];
    const void* W3 = d_in[9];
    const void* b3 = d_in[10];
    u16* ws = (u16*)d_ws;

    prep<<<512, 512, 0, stream>>>(eidx, ew, qembs, dummy, W1, b1, W2, b2, W3, b3, ws);
    fused<<<256, 1024, 0, stream>>>(allocs, ws, d_out);
}

// Round 12
// 146.890 us; speedup vs baseline: 2.4321x; 2.4321x over previous
//
#include <hip/hip_runtime.h>
#include <type_traits>

typedef __attribute__((ext_vector_type(8))) short short8;
typedef __attribute__((ext_vector_type(4))) short short4v;
typedef __attribute__((ext_vector_type(4))) float f32x4;
typedef unsigned short u16;
typedef unsigned int u32;

#define N_EDGES 448

// ws layout (u16 units); all-bf16 packs
#define WS_ADJA 0                    // 4096: A_norm, MFMA A-operand pack
#define WS_ADJB 4096                 // 4096: A_norm^T, MFMA B-operand pack
#define WS_W1   8192                 // 256x512
#define WS_W2   139264               // 512x512
#define WS_W3   401408               // 512x256
#define WS_DUM  532480               // dummy 256 | b1 512 | b2 512 | b3 256
#define WS_B1   (WS_DUM + 256)
#define WS_B2   (WS_DUM + 768)
#define WS_B3   (WS_DUM + 1280)
#define WS_QE   534528               // 1024x256 qembs as bf16, row-major
#define WS_FLAG 796672               // u32: 1 = f32 inputs, 0 = bf16

__device__ __forceinline__ float bf2f(u16 v) {
    u32 u = ((u32)v) << 16;
    return __builtin_bit_cast(float, u);
}
__device__ __forceinline__ u16 f2bf(float f) {          // RNE (prep)
    u32 u = __builtin_bit_cast(u32, f);
    u32 r = u + 0x7FFFu + ((u >> 16) & 1u);
    return (u16)(r >> 16);
}
__device__ __forceinline__ u16 f2bf_fast(float f) {     // round-half-up (hot)
    u32 u = __builtin_bit_cast(u32, f);
    return (u16)((u + 0x8000u) >> 16);
}
__device__ __forceinline__ float ldf(const void* p, int idx, u32 isf32) {
    return isf32 ? ((const float*)p)[idx] : bf2f(((const u16*)p)[idx]);
}

// ---------------------------------------------------------------------------
// prep: 512 blocks x 512 threads (proven ~10 us).
//   all blocks: 2 weight chunks (t<128) + qembs->bf16 copy (t>=256)
//   block 0: adjacency + flag;  block 1: biases/dummy
// ---------------------------------------------------------------------------
__global__ __launch_bounds__(512) void prep(
    const int* __restrict__ eidx, const void* __restrict__ ew,
    const void* __restrict__ qembs, const void* __restrict__ dummy,
    const void* __restrict__ W1, const void* __restrict__ b1,
    const void* __restrict__ W2, const void* __restrict__ b2,
    const void* __restrict__ W3, const void* __restrict__ b3,
    u16* __restrict__ ws) {
    const int t = threadIdx.x, bb = blockIdx.x;
    __shared__ u32 s_isf;
    if (t < 64) {
        const u16* qs = (const u16*)qembs;
        int c = 0;
#pragma unroll
        for (int j = 0; j < 4; j++) {
            u16 v = qs[(t * 4 + j) * 2];
            u32 e = (v >> 7) & 0xFF;
            c += (e >= 100 && e <= 134) ? 1 : 0;
        }
#pragma unroll
        for (int off = 32; off > 0; off >>= 1) c += __shfl_down(c, off, 64);
        if (t == 0) s_isf = (c < 128) ? 1u : 0u;
    }
    __syncthreads();
    const u32 isf32 = s_isf;

    if (t < 128) {
        const int bw = bb * 2 + (t >> 6);
        const int tl = t & 63;
        const void* src;
        int N, K32, dst, nt, kk;
        if (bw < 256)      { src = W1; N = 512; K32 = 8;  dst = WS_W1; nt = bw / 8;          kk = bw % 8; }
        else if (bw < 768) { src = W2; N = 512; K32 = 16; dst = WS_W2; nt = (bw - 256) / 16; kk = (bw - 256) % 16; }
        else               { src = W3; N = 256; K32 = 16; dst = WS_W3; nt = (bw - 768) / 16; kk = (bw - 768) % 16; }
        const int col = nt * 16 + (tl & 15);
        const int krow = kk * 32 + (tl >> 4) * 8;
        u16 v[8];
#pragma unroll
        for (int j = 0; j < 8; j++) v[j] = f2bf(ldf(src, (krow + j) * N + col, isf32));
        u16* o = ws + dst + (nt * K32 + kk) * 512 + tl * 8;
#pragma unroll
        for (int j = 0; j < 8; j++) o[j] = v[j];
    }
    if (t >= 256) {
        const int base = bb * 512 + (t - 256) * 2;
        ws[WS_QE + base]     = f2bf(ldf(qembs, base, isf32));
        ws[WS_QE + base + 1] = f2bf(ldf(qembs, base + 1, isf32));
    }
    if (bb == 1) {
#pragma unroll
        for (int j = 0; j < 4; j++) {
            int i = t + j * 512;
            if (i < 1792) {
                float v;
                if (i < 256)       v = ldf(dummy, i, isf32);
                else if (i < 768)  v = ldf(b1, i - 256, isf32);
                else if (i < 1280) v = ldf(b2, i - 768, isf32);
                else               v = ldf(b3, i - 1280, isf32);
                ws[WS_DUM + i] = f2bf(v);
            }
        }
    }
    if (bb == 0) {
        __shared__ float A[4096];
        __shared__ float deg[64];
        __shared__ float dinv[64];
        __shared__ int er[N_EDGES];
        __shared__ int ec[N_EDGES];
        __shared__ float ewf[N_EDGES];
        if (t < N_EDGES) {
            er[t] = eidx[t];
            ec[t] = eidx[N_EDGES + t];
            ewf[t] = ldf(ew, t, isf32);
        }
        if (t < 64) deg[t] = 1.0f;
        for (int i = t; i < 4096; i += 512) A[i] = 0.f;
        __syncthreads();
        if (t < N_EDGES) atomicAdd(&deg[ec[t]], ewf[t]);
        __syncthreads();
        if (t < 64) dinv[t] = 1.0f / sqrtf(deg[t]);
        __syncthreads();
        if (t < N_EDGES) atomicAdd(&A[ec[t] * 64 + er[t]], dinv[er[t]] * ewf[t] * dinv[ec[t]]);
        __syncthreads();
        if (t < 64) A[t * 64 + t] += dinv[t] * dinv[t];
        __syncthreads();
        for (int i = t; i < 4096; i += 512) {
            int chunk = i >> 9, m = (i >> 3) & 63, j = i & 7;
            ws[WS_ADJA + i] = f2bf(A[m * 64 + chunk * 8 + j]);
        }
        for (int i = t; i < 4096; i += 512) {
            int chunk = i >> 9, l = (i >> 3) & 63, j = i & 7;
            int ntc = chunk >> 1, kk = chunk & 1;
            int k = kk * 32 + (l >> 4) * 8 + j;
            int c2 = ntc * 16 + (l & 15);
            ws[WS_ADJB + i] = f2bf(A[c2 * 64 + k]);
        }
        if (t == 0) *(u32*)(ws + WS_FLAG) = isf32;
    }
}

// ---------------------------------------------------------------------------
// fused: pooling + 3 GCN layers. 512 blocks x 1024 threads (16 waves).
// Ping-pong BUF0/BUF1 (128 KB, 1 block/CU): one barrier per layer — no
// in-place WAR drain between K-loop and epilogue. 64-VGPR balanced; do not
// extend register liveness (R11: 2-elem loop -> spill, FETCH 10.5MB -> 335MB).
// ---------------------------------------------------------------------------
__global__ __launch_bounds__(1024, 4) void fused(
    const int* __restrict__ allocs, const u16* __restrict__ ws,
    void* __restrict__ out) {

    __shared__ __align__(16) u16 BUF0[64 * 512];   // 64 KB
    __shared__ __align__(16) u16 BUF1[64 * 512];   // 64 KB

    const int t = threadIdx.x, bb = blockIdx.x;
    const int wave = t >> 6, lane = t & 63, quad = lane >> 4, nl = lane & 15;
    const u32 isf32 = *(const u32*)(ws + WS_FLAG);

    // ---- pooling: counting sort (aux in BUF1) + wave gather -> X in BUF0 ----
    {
        int* LIST = (int*)BUF1;
        int* CNT  = LIST + 1024;
        int* SST  = CNT + 64;
        int* WOF  = SST + 64;
        if (t < 64) CNT[t] = 0;
        __syncthreads();
        const int myc = allocs[bb * 1024 + t];
        atomicAdd(&CNT[myc], 1);
        __syncthreads();
        if (t < 64) {
            int v = CNT[t], s = v;
#pragma unroll
            for (int off = 1; off < 64; off <<= 1) {
                int u = __shfl_up(s, off, 64);
                if (t >= off) s += u;
            }
            SST[t] = s - v;
            WOF[t] = s - v;
        }
        __syncthreads();
        {
            int pos = atomicAdd(&WOF[myc], 1);
            LIST[pos] = t;
        }
        __syncthreads();
        // wave owns cores wave*4..+3; lane owns dims lane*4..+3 (uint2 bf16)
        float dums[4];
#pragma unroll
        for (int jj = 0; jj < 4; jj++) dums[jj] = bf2f(ws[WS_DUM + lane * 4 + jj]);
        const u16* wsq = ws + WS_QE;
        for (int i = 0; i < 4; i++) {
            const int c = wave * 4 + i;
            const int L = CNT[c], S = SST[c];
            float vm0 = dums[0], vm1 = dums[1], vm2 = dums[2], vm3 = dums[3];
            for (int j = 0; j < L; j++) {
                int q = LIST[S + j];
                uint2 r = *(const uint2*)(wsq + q * 256 + lane * 4);
                vm0 = fmaxf(vm0, bf2f((u16)(r.x & 0xffff)));
                vm1 = fmaxf(vm1, bf2f((u16)(r.x >> 16)));
                vm2 = fmaxf(vm2, bf2f((u16)(r.y & 0xffff)));
                vm3 = fmaxf(vm3, bf2f((u16)(r.y >> 16)));
            }
            short4v p;
            p[0] = (short)f2bf_fast(vm0);
            p[1] = (short)f2bf_fast(vm1);
            p[2] = (short)f2bf_fast(vm2);
            p[3] = (short)f2bf_fast(vm3);
            *(short4v*)(BUF0 + (lane >> 1) * 512 + c * 8 + (lane & 1) * 4) = p;
        }
    }
    __syncthreads();

    // pinned A_norm^T B-operand frags (shared across both layerT calls)
    short8 adjB[4][2];
#pragma unroll
    for (int ntc = 0; ntc < 4; ntc++)
#pragma unroll
        for (int h = 0; h < 2; h++)
            adjB[ntc][h] = *(const short8*)(ws + WS_ADJB + (ntc * 2 + h) * 512 + lane * 8);

    // layerT: mm1 (2 stripes/wave) + transpose + agg + relu/bias -> OUT A-pack.
    // scr = wave's own stripe-1 output chunks (4w+2..3), consumed before the
    // s=1 epilogue overwrites them (validated in R9). One barrier at end.
    auto layerT = [&](auto K32c, const u16* __restrict__ W, const u16* __restrict__ bias,
                      const u16* __restrict__ IN, u16* __restrict__ OUT) {
        constexpr int K32 = decltype(K32c)::value;
        const int s0 = wave * 2;
        u16* scr = OUT + (wave * 4 + 2) * 512;
        f32x4 acc[2][4];
#pragma unroll
        for (int s = 0; s < 2; s++)
#pragma unroll
            for (int rt = 0; rt < 4; rt++) acc[s][rt] = f32x4{0.f, 0.f, 0.f, 0.f};
#pragma unroll
        for (int kk = 0; kk < K32; kk++) {
            short8 a[4], bch[2];
#pragma unroll
            for (int rt = 0; rt < 4; rt++)
                a[rt] = *(const short8*)(IN + (kk * 4 + quad) * 512 + (rt * 16 + nl) * 8);
#pragma unroll
            for (int s = 0; s < 2; s++)
                bch[s] = *(const short8*)(W + ((s0 + s) * K32 + kk) * 512 + lane * 8);
#pragma unroll
            for (int s = 0; s < 2; s++)
#pragma unroll
                for (int rt = 0; rt < 4; rt++)
                    acc[s][rt] = __builtin_amdgcn_mfma_f32_16x16x32_bf16(a[rt], bch[s], acc[s][rt], 0, 0, 0);
        }
#pragma unroll
        for (int s = 0; s < 2; s++) {
            const int nt = s0 + s;
            f32x4 agg[4];
#pragma unroll
            for (int ntc = 0; ntc < 4; ntc++) agg[ntc] = f32x4{0.f, 0.f, 0.f, 0.f};
#pragma unroll
            for (int h = 0; h < 2; h++) {
#pragma unroll
                for (int r2 = 0; r2 < 2; r2++) {
                    f32x4 v = acc[s][2 * h + r2];
                    short4v p;
#pragma unroll
                    for (int rr = 0; rr < 4; rr++) p[rr] = (short)f2bf_fast(v[rr]);
                    *(short4v*)(scr + nl * 40 + r2 * 16 + quad * 4) = p;
                }
                short8 hwf = *(const short8*)(scr + nl * 40 + quad * 8);
#pragma unroll
                for (int ntc = 0; ntc < 4; ntc++)
                    agg[ntc] = __builtin_amdgcn_mfma_f32_16x16x32_bf16(hwf, adjB[ntc][h], agg[ntc], 0, 0, 0);
            }
            float bv[4];
#pragma unroll
            for (int rr = 0; rr < 4; rr++) bv[rr] = bf2f(bias[nt * 16 + quad * 4 + rr]);
#pragma unroll
            for (int ntc = 0; ntc < 4; ntc++) {
                short4v p;
#pragma unroll
                for (int rr = 0; rr < 4; rr++)
                    p[rr] = (short)f2bf_fast(fmaxf(agg[ntc][rr] + bv[rr], 0.f));
                *(short4v*)(OUT + (nt * 2 + (quad >> 1)) * 512 + (ntc * 16 + nl) * 8 + (quad & 1) * 4) = p;
            }
        }
        __syncthreads();
    };

    // layer3: hw3 = h2 @ W3 (1 stripe/wave); B-pack -> OUT chunks 0..31.
    auto layer3 = [&](const u16* __restrict__ W, const u16* __restrict__ IN,
                      u16* __restrict__ OUT) {
        const int nt = wave;
        u16* scr = OUT + 16384 + wave * 640;   // chunks 32+ (dead region)
        f32x4 acc[4];
#pragma unroll
        for (int rt = 0; rt < 4; rt++) acc[rt] = f32x4{0.f, 0.f, 0.f, 0.f};
#pragma unroll
        for (int kk = 0; kk < 16; kk++) {
            short8 a[4];
#pragma unroll
            for (int rt = 0; rt < 4; rt++)
                a[rt] = *(const short8*)(IN + (kk * 4 + quad) * 512 + (rt * 16 + nl) * 8);
            short8 bch = *(const short8*)(W + (nt * 16 + kk) * 512 + lane * 8);
#pragma unroll
            for (int rt = 0; rt < 4; rt++)
                acc[rt] = __builtin_amdgcn_mfma_f32_16x16x32_bf16(a[rt], bch, acc[rt], 0, 0, 0);
        }
#pragma unroll
        for (int h = 0; h < 2; h++) {
#pragma unroll
            for (int r2 = 0; r2 < 2; r2++) {
                f32x4 v = acc[2 * h + r2];
                short4v p;
#pragma unroll
                for (int rr = 0; rr < 4; rr++) p[rr] = (short)f2bf_fast(v[rr]);
                *(short4v*)(scr + nl * 40 + r2 * 16 + quad * 4) = p;
            }
            short8 hwf = *(const short8*)(scr + nl * 40 + quad * 8);
            *(short8*)(OUT + (nt * 2 + h) * 512 + lane * 8) = hwf;
        }
        __syncthreads();
    };

    layerT(std::integral_constant<int, 8>{},  ws + WS_W1, ws + WS_B1, BUF0, BUF1);
    layerT(std::integral_constant<int, 16>{}, ws + WS_W2, ws + WS_B2, BUF1, BUF0);
    layer3(ws + WS_W3, BUF0, BUF1);

    // final: out = relu(A_norm @ hw3 + b3); stage f32 in BUF0, coalesced store
    {
        const int rt2 = wave & 3, nt0 = (wave >> 2) * 4;
        short8 aA[2];
#pragma unroll
        for (int h = 0; h < 2; h++)
            aA[h] = *(const short8*)(ws + WS_ADJA + (h * 4 + quad) * 512 + (rt2 * 16 + nl) * 8);
        f32x4 accv[4];
#pragma unroll
        for (int ni = 0; ni < 4; ni++) {
            const int nt = nt0 + ni;
            short8 b0v = *(const short8*)(BUF1 + (nt * 2 + 0) * 512 + lane * 8);
            short8 b1v = *(const short8*)(BUF1 + (nt * 2 + 1) * 512 + lane * 8);
            f32x4 a = f32x4{0.f, 0.f, 0.f, 0.f};
            a = __builtin_amdgcn_mfma_f32_16x16x32_bf16(aA[0], b0v, a, 0, 0, 0);
            a = __builtin_amdgcn_mfma_f32_16x16x32_bf16(aA[1], b1v, a, 0, 0, 0);
            accv[ni] = a;
        }
        float* Hf = (float*)BUF0;   // BUF0 dead after layer3's end barrier
#pragma unroll
        for (int ni = 0; ni < 4; ni++) {
            const int n = (nt0 + ni) * 16 + nl;
            const float bv = bf2f(ws[WS_B3 + n]);
#pragma unroll
            for (int rr = 0; rr < 4; rr++) {
                const int m2 = rt2 * 16 + quad * 4 + rr;
                Hf[m2 * 256 + n] = fmaxf(accv[ni][rr] + bv, 0.f);
            }
        }
        __syncthreads();
        if (isf32) {
            float4* outv = (float4*)((float*)out + (size_t)bb * 16384);
            const float4* Hv = (const float4*)Hf;
#pragma unroll
            for (int p4 = 0; p4 < 4; p4++) outv[p4 * 1024 + t] = Hv[p4 * 1024 + t];
        } else {
            u16* outu = (u16*)out + (size_t)bb * 16384;
#pragma unroll
            for (int p4 = 0; p4 < 4; p4++) {
                const int idx = (p4 * 1024 + t) * 4;
                float4 v = *(const float4*)(Hf + idx);
                short4v pk;
                pk[0] = (short)f2bf_fast(v.x); pk[1] = (short)f2bf_fast(v.y);
                pk[2] = (short)f2bf_fast(v.z); pk[3] = (short)f2bf_fast(v.w);
                *(short4v*)(outu + idx) = pk;
            }
        }
    }
}

// ---------------------------------------------------------------------------
extern "C" void kernel_launch(void* const* d_in, const int* in_sizes, int n_in,
                              void* d_out, int out_size, void* d_ws, size_t ws_size,
                              hipStream_t stream) {
    const int* allocs = (const int*)d_in[0];
    const void* qembs = d_in[1];
    const void* dummy = d_in[2];
    const int* eidx   = (const int*)d_in[3];
    const void* ew    = d_in[4];
    const void* W1 = d_in[5];
    const void* b1 = d_in[6];
    const void* W2 = d_in[7];
    const void* b2 = d_in[8];
    const void* W3 = d_in[9];
    const void* b3 = d_in[10];
    u16* ws = (u16*)d_ws;

    prep<<<512, 512, 0, stream>>>(eidx, ew, qembs, dummy, W1, b1, W2, b2, W3, b3, ws);
    fused<<<512, 1024, 0, stream>>>(allocs, ws, d_out);
}